// Round 1
// baseline (791.852 us; speedup 1.0000x reference)
//
#include <hip/hip_runtime.h>
#include <math.h>

#define N_NODESC 50000
#define N_EDGESC 600000
#define LOG2C 0.69314718055994530942f
#define EPSC 1e-5f

// ---------------- CSR build ----------------

__global__ void k_count(const int* __restrict__ dst, int* __restrict__ counts) {
  int i = blockIdx.x * blockDim.x + threadIdx.x;
  if (i < N_EDGESC) atomicAdd(&counts[dst[i]], 1);
}

__global__ void k_scan(const int* __restrict__ counts, int* __restrict__ offsets,
                       int* __restrict__ cursor) {
  __shared__ int ssum[256];
  const int tid = threadIdx.x;
  const int chunk = (N_NODESC + 255) / 256;
  int lo = tid * chunk;
  int hi = lo + chunk; if (hi > N_NODESC) hi = N_NODESC;
  int s = 0;
  for (int i = lo; i < hi; ++i) s += counts[i];
  ssum[tid] = s;
  __syncthreads();
  for (int st = 1; st < 256; st <<= 1) {
    int t = (tid >= st) ? ssum[tid - st] : 0;
    __syncthreads();
    ssum[tid] += t;
    __syncthreads();
  }
  int base = (tid == 0) ? 0 : ssum[tid - 1];
  for (int i = lo; i < hi; ++i) {
    offsets[i] = base;
    cursor[i]  = base;
    base += counts[i];
  }
}

__global__ void k_fill(const int* __restrict__ dst, int* __restrict__ cursor,
                       int* __restrict__ edge_list) {
  int i = blockIdx.x * blockDim.x + threadIdx.x;
  if (i < N_EDGESC) {
    int d = dst[i];
    int p = atomicAdd(&cursor[d], 1);
    edge_list[p] = i;
  }
}

// ---------------- gather: one wave per node, lanes hold 2 cols ----------------

__global__ __launch_bounds__(256)
void k_gather(const float* __restrict__ e, const int* __restrict__ offsets,
              const int* __restrict__ counts, const int* __restrict__ edge_list,
              float* __restrict__ agg) {
  int gw   = (int)((blockIdx.x * (unsigned)blockDim.x + threadIdx.x) >> 6);
  int lane = threadIdx.x & 63;
  if (gw >= N_NODESC) return;
  int off = offsets[gw];
  int deg = counts[gw];
  const float2* e2 = (const float2*)e;
  float2 acc = make_float2(0.f, 0.f);
  int j = 0;
  for (; j + 2 <= deg; j += 2) {
    int e0 = edge_list[off + j];
    int e1 = edge_list[off + j + 1];
    float2 a = e2[e0 * 64 + lane];
    float2 b = e2[e1 * 64 + lane];
    acc.x += a.x + b.x;
    acc.y += a.y + b.y;
  }
  if (j < deg) {
    int e0 = edge_list[off + j];
    float2 a = e2[e0 * 64 + lane];
    acc.x += a.x;
    acc.y += a.y;
  }
  ((float2*)agg)[gw * 64 + lane] = acc;
}

// ---------------- fused MLP + LayerNorm + residual ----------------
// Block: 256 threads = 4 waves. Each wave owns 8 nodes; lane owns cols j, j+64.
// LDS: W11 (64KB, swizzled) + W12 (64KB, swizzled) + sH (16KB wave-private) = 144KB.
// agg is read from, and the result written to, the SAME buffer (d_out) — same
// rows per wave, reads complete before writes, no cross-wave overlap.

__global__ __launch_bounds__(256, 1)
void k_node(float* aggout,
            const float* __restrict__ v,
            const float* __restrict__ W11, const float* __restrict__ b11,
            const float* __restrict__ W12, const float* __restrict__ b12,
            const float* __restrict__ lnw, const float* __restrict__ lnb,
            int n_tiles) {
  extern __shared__ float smem[];
  float4* sW1v = (float4*)smem;          // 4096 float4 = 64KB
  float4* sW2v = sW1v + 4096;            // 64KB
  float*  sH   = smem + 32768;           // 4096 floats = 16KB
  const int tid = threadIdx.x;

  // stage weights with XOR-swizzled float4 granules: g' = g ^ (row & 7)
  const float4* W1g = (const float4*)W11;
  const float4* W2g = (const float4*)W12;
  #pragma unroll 4
  for (int i4 = tid; i4 < 4096; i4 += 256) {
    int jj = i4 >> 5, k4 = i4 & 31;
    int sidx = (jj << 5) | (k4 ^ (jj & 7));
    sW1v[sidx] = W1g[i4];
    sW2v[sidx] = W2g[i4];
  }
  __syncthreads();

  const int lane = tid & 63;
  const int wv   = tid >> 6;
  const int j0 = lane, j1 = lane + 64;
  const float bb11_0 = b11[j0], bb11_1 = b11[j1];
  const float bb12_0 = b12[j0], bb12_1 = b12[j1];
  const float lw0 = lnw[j0], lw1 = lnw[j1];
  const float lb0 = lnb[j0], lb1 = lnb[j1];
  float*  sHrow  = sH + wv * (8 * 128);
  float4* sHrow4 = (float4*)sHrow;

  for (int tile = blockIdx.x; tile < n_tiles; tile += gridDim.x) {
    const int node0 = tile * 32 + wv * 8;
    if (node0 >= N_NODESC) continue;   // 50000 % 8 == 0: waves fully valid or fully idle
    const float4* arow = ((const float4*)aggout) + (size_t)node0 * 32;

    // GEMV1: h1 = ssp(agg @ W11^T + b11)
    float acc0[8], acc1[8];
    #pragma unroll
    for (int nn = 0; nn < 8; ++nn) { acc0[nn] = bb11_0; acc1[nn] = bb11_1; }

    #pragma unroll 2
    for (int k4 = 0; k4 < 32; ++k4) {
      float4 w0 = sW1v[(j0 << 5) | (k4 ^ (j0 & 7))];
      float4 w1 = sW1v[(j1 << 5) | (k4 ^ (j1 & 7))];
      #pragma unroll
      for (int nn = 0; nn < 8; ++nn) {
        float4 a = arow[nn * 32 + k4];   // wave-uniform 16B read (coalesced broadcast)
        acc0[nn] = fmaf(w0.x, a.x, fmaf(w0.y, a.y, fmaf(w0.z, a.z, fmaf(w0.w, a.w, acc0[nn]))));
        acc1[nn] = fmaf(w1.x, a.x, fmaf(w1.y, a.y, fmaf(w1.z, a.z, fmaf(w1.w, a.w, acc1[nn]))));
      }
    }

    #pragma unroll
    for (int nn = 0; nn < 8; ++nn) {
      float x0 = acc0[nn], x1 = acc1[nn];
      sHrow[nn * 128 + j0] = fmaxf(x0, 0.f) + log1pf(expf(-fabsf(x0))) - LOG2C;
      sHrow[nn * 128 + j1] = fmaxf(x1, 0.f) + log1pf(expf(-fabsf(x1))) - LOG2C;
    }
    // sH is wave-private: no __syncthreads needed, in-wave LDS ordering suffices

    // GEMV2: h2 = h1 @ W12^T + b12
    float d0[8], d1[8];
    #pragma unroll
    for (int nn = 0; nn < 8; ++nn) { d0[nn] = bb12_0; d1[nn] = bb12_1; }

    #pragma unroll 2
    for (int k4 = 0; k4 < 32; ++k4) {
      float4 w0 = sW2v[(j0 << 5) | (k4 ^ (j0 & 7))];
      float4 w1 = sW2v[(j1 << 5) | (k4 ^ (j1 & 7))];
      #pragma unroll
      for (int nn = 0; nn < 8; ++nn) {
        float4 a = sHrow4[nn * 32 + k4]; // uniform LDS read -> broadcast, conflict-free
        d0[nn] = fmaf(w0.x, a.x, fmaf(w0.y, a.y, fmaf(w0.z, a.z, fmaf(w0.w, a.w, d0[nn]))));
        d1[nn] = fmaf(w1.x, a.x, fmaf(w1.y, a.y, fmaf(w1.z, a.z, fmaf(w1.w, a.w, d1[nn]))));
      }
    }

    // LayerNorm over 128 cols (spread as 2 per lane across 64 lanes) + residual
    #pragma unroll
    for (int nn = 0; nn < 8; ++nn) {
      float s  = d0[nn] + d1[nn];
      float ss = fmaf(d0[nn], d0[nn], d1[nn] * d1[nn]);
      #pragma unroll
      for (int o = 32; o >= 1; o >>= 1) {
        s  += __shfl_xor(s, o, 64);
        ss += __shfl_xor(ss, o, 64);
      }
      const float mu   = s * (1.0f / 128.0f);
      const float varr = fmaxf(ss * (1.0f / 128.0f) - mu * mu, 0.f);
      const float rstd = rsqrtf(varr + EPSC);
      const int row = node0 + nn;
      const float vv0 = v[row * 128 + j0];
      const float vv1 = v[row * 128 + j1];
      aggout[row * 128 + j0] = fmaf((d0[nn] - mu) * rstd, lw0, lb0) + vv0;
      aggout[row * 128 + j1] = fmaf((d1[nn] - mu) * rstd, lw1, lb1) + vv1;
    }
  }
}

// ---------------- launch ----------------

extern "C" void kernel_launch(void* const* d_in, const int* in_sizes, int n_in,
                              void* d_out, int out_size, void* d_ws, size_t ws_size,
                              hipStream_t stream) {
  const float* v   = (const float*)d_in[0];
  const float* e   = (const float*)d_in[1];
  const int*   ei  = (const int*)d_in[2];
  // d_in[3] = v1_size (unused: same weights on both halves)
  const float* W11 = (const float*)d_in[4];
  const float* b11 = (const float*)d_in[5];
  const float* W12 = (const float*)d_in[6];
  const float* b12 = (const float*)d_in[7];
  const float* lnw = (const float*)d_in[8];
  const float* lnb = (const float*)d_in[9];
  float* out = (float*)d_out;

  int* counts    = (int*)d_ws;
  int* offsets   = counts  + N_NODESC;
  int* cursor    = offsets + N_NODESC;
  int* edge_list = cursor  + N_NODESC;   // E ints; total ws use ~3MB

  const int* dst = ei + N_EDGESC;        // edge_index row 1 = destinations

  hipMemsetAsync(counts, 0, N_NODESC * sizeof(int), stream);
  k_count<<<(N_EDGESC + 255) / 256, 256, 0, stream>>>(dst, counts);
  k_scan<<<1, 256, 0, stream>>>(counts, offsets, cursor);
  k_fill<<<(N_EDGESC + 255) / 256, 256, 0, stream>>>(dst, cursor, edge_list);
  k_gather<<<(N_NODESC * 64 + 255) / 256, 256, 0, stream>>>(e, offsets, counts, edge_list, out);

  hipFuncSetAttribute((const void*)k_node, hipFuncAttributeMaxDynamicSharedMemorySize, 147456);
  const int n_tiles = (N_NODESC + 31) / 32;
  k_node<<<256, 256, 147456, stream>>>(out, v, W11, b11, W12, b12, lnw, lnb, n_tiles);
}